// Round 1
// baseline (38993.033 us; speedup 1.0000x reference)
//
#include <hip/hip_runtime.h>
#include <math.h>

// ---------------------------------------------------------------------------
// Fast-but-accurate transcendentals (f32, HW v_exp based)
// ---------------------------------------------------------------------------
__device__ __forceinline__ float tanh_fast(float x) {
    // tanh(x) = (e^{2x}-1)/(e^{2x}+1); clamp so e^{2x} never overflows.
    float xc = fminf(fmaxf(x, -15.0f), 15.0f);
    float e  = __expf(2.0f * xc);
    return (e - 1.0f) / (e + 1.0f);
}

__device__ __forceinline__ float sinh_fast(float x) {
    float e = __expf(x);
    return 0.5f * (e - 1.0f / e);
}

__device__ __forceinline__ float step_fct(float x) {
    return 0.5f * (tanh_fast(5.0f * x) + 1.0f);
}

// ---------------------------------------------------------------------------
// Kernel 1: sequential RK4 scan. ONE block, 128 threads (2 waves).
// Thread j owns MLP column j: W1[:,j], W2[:,j] (128 VGPRs), W3[j,:].
// ---------------------------------------------------------------------------
extern "C" __global__ void __launch_bounds__(128, 1)
scan_kernel(const float* __restrict__ x,
            const float* __restrict__ t_eval,
            const float* __restrict__ precp,
            const float* __restrict__ temp,
            const float* __restrict__ lday,
            const float* __restrict__ W1, const float* __restrict__ b1,
            const float* __restrict__ W2, const float* __restrict__ b2,
            const float* __restrict__ W3, const float* __restrict__ b3,
            float* __restrict__ sol, int T)
{
    const int j    = threadIdx.x;   // column 0..127
    const int lane = j & 63;
    const int wv   = j >> 6;

    __shared__ float h1s[128];
    __shared__ float red[2][5];

    // ---- preload weights into registers (all statically indexed) ----
    float w1c[4], w2c[128], w3r[5];
#pragma unroll
    for (int i = 0; i < 4; ++i)   w1c[i] = W1[i * 128 + j];
    const float b1j = b1[j];
#pragma unroll
    for (int i = 0; i < 128; ++i) w2c[i] = W2[i * 128 + j];
    const float b2j = b2[j];
#pragma unroll
    for (int k = 0; k < 5; ++k)   w3r[k] = W3[j * 5 + k];
    const float b30 = b3[0], b31 = b3[1], b32 = b3[2], b33 = b3[3], b34 = b3[4];

    float S0 = x[0], S1 = x[1];
    if (j == 0) { sol[0] = S0; sol[1] = S1; }

    // rhs: uniform inputs (z0,z1,precp,temp,lday) -> uniform (d0,d1)
    auto rhs = [&](float z0, float z1, float pr, float tm, float ld,
                   float& d0, float& d1) {
        // layer 1 (per-lane column)
        float a = b1j;
        a = fmaf(z0, w1c[0], a);
        a = fmaf(z1, w1c[1], a);
        a = fmaf(pr, w1c[2], a);
        a = fmaf(tm, w1c[3], a);
        h1s[j] = tanh_fast(a);
        __syncthreads();                                   // B1
        // layer 2: broadcast h1 from LDS, 128 register FMAs
        float acc0 = 0.f, acc1 = 0.f, acc2 = 0.f, acc3 = 0.f;
#pragma unroll
        for (int i = 0; i < 128; i += 4) {
            const float4 hv = *reinterpret_cast<const float4*>(&h1s[i]);
            acc0 = fmaf(hv.x, w2c[i + 0], acc0);
            acc1 = fmaf(hv.y, w2c[i + 1], acc1);
            acc2 = fmaf(hv.z, w2c[i + 2], acc2);
            acc3 = fmaf(hv.w, w2c[i + 3], acc3);
        }
        const float h2 = tanh_fast(((acc0 + acc1) + (acc2 + acc3)) + b2j);
        // layer 3 partials + 64-lane butterfly reduce
        float p0 = h2 * w3r[0], p1 = h2 * w3r[1], p2 = h2 * w3r[2],
              p3 = h2 * w3r[3], p4 = h2 * w3r[4];
#pragma unroll
        for (int off = 32; off >= 1; off >>= 1) {
            p0 += __shfl_xor(p0, off);
            p1 += __shfl_xor(p1, off);
            p2 += __shfl_xor(p2, off);
            p3 += __shfl_xor(p3, off);
            p4 += __shfl_xor(p4, off);
        }
        if (lane == 0) {
            red[wv][0] = p0; red[wv][1] = p1; red[wv][2] = p2;
            red[wv][3] = p3; red[wv][4] = p4;
        }
        __syncthreads();                                   // B2
        const float o0 = red[0][0] + red[1][0] + b30;
        const float o1 = red[0][1] + red[1][1] + b31;
        const float o2 = red[0][2] + red[1][2] + b32;
        const float o3 = red[0][3] + red[1][3] + b33;
        const float o4 = red[0][4] + red[1][4] + b34;

        // epilogue (uniform, redundantly on all lanes)
        const float sS0 = step_fct(z0);
        const float sS1 = step_fct(z1);
        const float sNT = step_fct(-tm);
        const float melt = sS0 * sinh_fast(o2);            // relu(step)=step (>0)
        d0 = fmaxf(sinh_fast(o3) * sNT, 0.0f) - melt;
        d1 = fmaxf(sinh_fast(o4), 0.0f) + melt
             - sS1 * ld * __expf(o0) - sS1 * __expf(o1);
    };

#pragma unroll 1
    for (int n = 0; n < T - 1; ++n) {
        const float t0 = t_eval[n], t1 = t_eval[n + 1];
        const float hh = t1 - t0;
        const float pA = precp[n], pB = precp[n + 1];
        const float tA = temp[n],  tB = temp[n + 1];
        const float lA = lday[n],  lB = lday[n + 1];
        const float pM = 0.5f * (pA + pB);
        const float tM = 0.5f * (tA + tB);
        const float lM = 0.5f * (lA + lB);

        float k10, k11, k20, k21, k30, k31, k40, k41;
        rhs(S0, S1, pA, tA, lA, k10, k11);
        rhs(fmaf(0.5f * hh, k10, S0), fmaf(0.5f * hh, k11, S1), pM, tM, lM, k20, k21);
        rhs(fmaf(0.5f * hh, k20, S0), fmaf(0.5f * hh, k21, S1), pM, tM, lM, k30, k31);
        rhs(fmaf(hh, k30, S0),        fmaf(hh, k31, S1),        pB, tB, lB, k40, k41);

        const float c = hh / 6.0f;
        S0 = S0 + c * (k10 + 2.0f * (k20 + k30) + k40);
        S1 = S1 + c * (k11 + 2.0f * (k21 + k31) + k41);
        if (j == 0) {
            sol[2 * (n + 1)]     = S0;
            sol[2 * (n + 1) + 1] = S1;
        }
    }
}

// ---------------------------------------------------------------------------
// Kernel 2: y_hat[t] = exp(mlp([sol0,sol1,x2,x3])[1]) — fully parallel.
// ---------------------------------------------------------------------------
extern "C" __global__ void __launch_bounds__(128)
out_kernel(const float* __restrict__ x,
           const float* __restrict__ sol,
           const float* __restrict__ W1, const float* __restrict__ b1,
           const float* __restrict__ W2, const float* __restrict__ b2,
           const float* __restrict__ W3, const float* __restrict__ b3,
           float* __restrict__ y, int T)
{
    const int j    = threadIdx.x;
    const int lane = j & 63;
    const int wv   = j >> 6;

    __shared__ float h1s[128];
    __shared__ float red[2];

    float w1c[4], w2c[128];
#pragma unroll
    for (int i = 0; i < 4; ++i)   w1c[i] = W1[i * 128 + j];
    const float b1j = b1[j];
#pragma unroll
    for (int i = 0; i < 128; ++i) w2c[i] = W2[i * 128 + j];
    const float b2j = b2[j];
    const float w31 = W3[j * 5 + 1];
    const float b31 = b3[1];

#pragma unroll 1
    for (int r = blockIdx.x; r < T; r += gridDim.x) {
        const float z0 = sol[2 * r], z1 = sol[2 * r + 1];
        const float z2 = x[4 * r + 2], z3 = x[4 * r + 3];
        float a = b1j;
        a = fmaf(z0, w1c[0], a);
        a = fmaf(z1, w1c[1], a);
        a = fmaf(z2, w1c[2], a);
        a = fmaf(z3, w1c[3], a);
        h1s[j] = tanh_fast(a);
        __syncthreads();                                   // B1
        float acc0 = 0.f, acc1 = 0.f, acc2 = 0.f, acc3 = 0.f;
#pragma unroll
        for (int i = 0; i < 128; i += 4) {
            const float4 hv = *reinterpret_cast<const float4*>(&h1s[i]);
            acc0 = fmaf(hv.x, w2c[i + 0], acc0);
            acc1 = fmaf(hv.y, w2c[i + 1], acc1);
            acc2 = fmaf(hv.z, w2c[i + 2], acc2);
            acc3 = fmaf(hv.w, w2c[i + 3], acc3);
        }
        const float h2 = tanh_fast(((acc0 + acc1) + (acc2 + acc3)) + b2j);
        float p = h2 * w31;
#pragma unroll
        for (int off = 32; off >= 1; off >>= 1)
            p += __shfl_xor(p, off);
        if (lane == 0) red[wv] = p;
        __syncthreads();                                   // B2
        if (j == 0) y[r] = __expf(red[0] + red[1] + b31);
    }
}

// ---------------------------------------------------------------------------
extern "C" void kernel_launch(void* const* d_in, const int* in_sizes, int n_in,
                              void* d_out, int out_size, void* d_ws, size_t ws_size,
                              hipStream_t stream)
{
    const float* x      = (const float*)d_in[0];
    const float* t_eval = (const float*)d_in[1];
    // d_in[2] = t_grid : arange(T), implicitly used as unit grid
    const float* precp  = (const float*)d_in[3];
    const float* temp   = (const float*)d_in[4];
    const float* lday   = (const float*)d_in[5];
    const float* W1     = (const float*)d_in[6];
    const float* b1     = (const float*)d_in[7];
    const float* W2     = (const float*)d_in[8];
    const float* b2     = (const float*)d_in[9];
    const float* W3     = (const float*)d_in[10];
    const float* b3     = (const float*)d_in[11];
    float*       y      = (float*)d_out;
    float*       sol    = (float*)d_ws;      // T*2 floats = 58.4 KB
    const int    T      = in_sizes[1];

    hipLaunchKernelGGL(scan_kernel, dim3(1), dim3(128), 0, stream,
                       x, t_eval, precp, temp, lday,
                       W1, b1, W2, b2, W3, b3, sol, T);
    hipLaunchKernelGGL(out_kernel, dim3(256), dim3(128), 0, stream,
                       x, sol, W1, b1, W2, b2, W3, b3, y, T);
}